// Round 3
// baseline (261.225 us; speedup 1.0000x reference)
//
#include <hip/hip_runtime.h>

#define ROWS_ 131072      // S*N*B = 16*256*32
#define NNZ_  524288
#define E_    256
#define E4_   64          // E/4 float4s per row
#define LOG2NNZ_ 19       // 2^19 == NNZ_, fixed-iteration binary search

typedef float f32x4 __attribute__((ext_vector_type(4)));   // clang vector: OK for nontemporal builtins

// ---------------------------------------------------------------------------
// Single fused kernel. 65536 blocks of 256 threads:
//   even blocks -> dense node-embed gather (one thread per output float4)
//   odd  blocks -> SpMM segment-sum (one wave per output row)
// Interleaving keeps write-heavy (A) and gather-heavy (C) waves co-resident
// on every CU so the HBM-write pipe and L3-read pipe overlap.
// Row bounds come from an inline fixed-19-step binary search over the sorted
// COO rows (lanes 0/1 search row and row+1), eliminating the row_ptr kernel.
// Nontemporal stores keep the 51 MB tok table resident in L3.
// ---------------------------------------------------------------------------
__global__ __launch_bounds__(256) void fused_kernel(
    const int*   __restrict__ node_idx,
    const int*   __restrict__ rows,
    const int*   __restrict__ cols,
    const float* __restrict__ vals,
    const f32x4* __restrict__ w,
    const f32x4* __restrict__ tok,
    f32x4*       __restrict__ out1,
    f32x4*       __restrict__ out2) {

    int bid = blockIdx.x;

    if ((bid & 1) == 0) {
        // ---- dense node-embed gather ----
        int tid  = (bid >> 1) * 256 + threadIdx.x;   // one float4 each
        int row  = tid >> 6;
        int l    = tid & 63;
        int node = node_idx[row];                    // wave-uniform broadcast
        f32x4 t  = w[node * E4_ + l];                // 128 KiB table, L2-hit
        __builtin_nontemporal_store(t, &out1[tid]);
    } else {
        // ---- SpMM segment-sum: one wave per row ----
        int gtid = (bid >> 1) * 256 + threadIdx.x;
        int row  = gtid >> 6;
        int lane = threadIdx.x & 63;

        // inline lower_bound: lane 0 searches `row`, lane 1 searches `row+1`
        int target = row + (lane != 0 ? 1 : 0);
        int lo = 0, hi = NNZ_;
        #pragma unroll
        for (int it = 0; it < LOG2NNZ_; ++it) {
            int mid = (lo + hi) >> 1;
            if (rows[mid] < target) lo = mid + 1; else hi = mid;
        }
        int start = __shfl(lo, 0);
        int end   = __shfl(lo, 1);
        int cnt   = end - start;

        f32x4 acc = (f32x4)(0.f);
        for (int base = 0; base < cnt; base += 64) {
            int n = cnt - base; if (n > 64) n = 64;
            // parallel preload of (col,val) pairs — breaks the
            // col-load -> gather dependent chain
            int   idx = start + base + lane;
            int   c_l = (lane < n) ? cols[idx] : 0;
            float v_l = (lane < n) ? vals[idx] : 0.f;
            for (int j = 0; j < n; ++j) {
                int c = __builtin_amdgcn_readlane(c_l, j);               // SGPR col
                int vbits = __builtin_amdgcn_readlane(__float_as_int(v_l), j);
                float v = __int_as_float(vbits);
                f32x4 t = tok[c * E4_ + lane];       // coalesced 1 KiB gather
                acc += v * t;
            }
        }
        __builtin_nontemporal_store(acc, &out2[(size_t)row * E4_ + lane]);
    }
}

extern "C" void kernel_launch(void* const* d_in, const int* in_sizes, int n_in,
                              void* d_out, int out_size, void* d_ws, size_t ws_size,
                              hipStream_t stream) {
    const int*   node_idx  = (const int*)d_in[0];
    const int*   spmm_rows = (const int*)d_in[1];
    const int*   spmm_cols = (const int*)d_in[2];
    const float* spmm_vals = (const float*)d_in[3];
    const float* node_w    = (const float*)d_in[4];
    const float* tok       = (const float*)d_in[5];

    f32x4* out1 = (f32x4*)d_out;                               // node_embed
    f32x4* out2 = out1 + (size_t)ROWS_ * E4_;                  // node_val_embed

    // A-half: ROWS_*E4_/256 = 32768 blocks; C-half: ROWS_/4 = 32768 blocks
    fused_kernel<<<65536, 256, 0, stream>>>(
        node_idx, spmm_rows, spmm_cols, spmm_vals,
        (const f32x4*)node_w, (const f32x4*)tok, out1, out2);
}

// Round 4
// 126.632 us; speedup vs baseline: 2.0629x; 2.0629x over previous
//
#include <hip/hip_runtime.h>

#define ROWS_ 131072      // S*N*B = 16*256*32
#define NNZ_  524288
#define E_    256
#define E4_   64          // E/4 float4s per row
#define LOG2NNZ_ 19       // 2^19 == NNZ_, fixed-iteration binary search

typedef float f32x4 __attribute__((ext_vector_type(4)));

// ---------------------------------------------------------------------------
// Kernel B: dense CSR row_start build. 64 searches per wave (all lanes
// active) — this was fast in round 1; the per-wave inline search in round 3
// (2/64 lanes active, 19 serial dependent loads per wave) was the regression.
// ---------------------------------------------------------------------------
__global__ __launch_bounds__(256) void row_ptr_kernel(
    const int* __restrict__ rows, int* __restrict__ row_start) {
    int r = blockIdx.x * blockDim.x + threadIdx.x;
    if (r > ROWS_) return;
    int lo = 0, hi = NNZ_;
    #pragma unroll
    for (int it = 0; it < LOG2NNZ_; ++it) {
        int mid = (lo + hi) >> 1;
        if (rows[mid] < r) lo = mid + 1; else hi = mid;
    }
    row_start[r] = lo;
}

// ---------------------------------------------------------------------------
// Kernel F: one wave per output row, fusing BOTH outputs for that row:
//  - out1 row: node_idx[row] (uniform) -> gather 1 KiB from the 128 KiB
//    node_embed table (L2-resident) -> coalesced store. Issued FIRST so the
//    store drains while the SpMM loop runs.
//  - out2 row: SpMM segment-sum. (col,val) pairs preloaded 64-at-a-time in
//    one parallel coalesced load, broadcast via readlane -> all tok gathers
//    are independent (no load->address dependent chain), plain stores.
// ---------------------------------------------------------------------------
__global__ __launch_bounds__(256) void fused_row_kernel(
    const int*   __restrict__ node_idx,
    const int*   __restrict__ row_start,
    const int*   __restrict__ cols,
    const float* __restrict__ vals,
    const f32x4* __restrict__ w,
    const f32x4* __restrict__ tok,
    f32x4*       __restrict__ out1,
    f32x4*       __restrict__ out2) {

    int gtid = blockIdx.x * blockDim.x + threadIdx.x;
    int row  = gtid >> 6;
    int lane = threadIdx.x & 63;

    // ---- dense node-embed half ----
    int node = node_idx[row];                 // wave-uniform
    f32x4 t0 = w[node * E4_ + lane];          // L2-hit gather
    out1[(size_t)row * E4_ + lane] = t0;

    // ---- SpMM half ----
    int start = row_start[row];
    int end   = row_start[row + 1];
    int cnt   = end - start;

    f32x4 acc = (f32x4)(0.f);
    for (int base = 0; base < cnt; base += 64) {
        int n = cnt - base; if (n > 64) n = 64;
        int   idx = start + base + lane;
        int   c_l = (lane < n) ? cols[idx] : 0;
        float v_l = (lane < n) ? vals[idx] : 0.f;
        for (int j = 0; j < n; ++j) {
            int   c = __builtin_amdgcn_readlane(c_l, j);   // SGPR col -> saddr gather
            int   vbits = __builtin_amdgcn_readlane(__float_as_int(v_l), j);
            float v = __int_as_float(vbits);
            f32x4 t = tok[c * E4_ + lane];                 // coalesced 1 KiB gather
            acc += v * t;
        }
    }
    out2[(size_t)row * E4_ + lane] = acc;
}

extern "C" void kernel_launch(void* const* d_in, const int* in_sizes, int n_in,
                              void* d_out, int out_size, void* d_ws, size_t ws_size,
                              hipStream_t stream) {
    const int*   node_idx  = (const int*)d_in[0];
    const int*   spmm_rows = (const int*)d_in[1];
    const int*   spmm_cols = (const int*)d_in[2];
    const float* spmm_vals = (const float*)d_in[3];
    const float* node_w    = (const float*)d_in[4];
    const float* tok       = (const float*)d_in[5];

    f32x4* out1 = (f32x4*)d_out;                     // node_embed
    f32x4* out2 = out1 + (size_t)ROWS_ * E4_;        // node_val_embed
    int*   row_start = (int*)d_ws;                   // (ROWS_+1) ints

    row_ptr_kernel<<<(ROWS_ + 1 + 255) / 256, 256, 0, stream>>>(
        spmm_rows, row_start);

    // one wave per row, 4 waves per block -> 32768 blocks
    fused_row_kernel<<<ROWS_ / 4, 256, 0, stream>>>(
        node_idx, row_start, spmm_cols, spmm_vals,
        (const f32x4*)node_w, (const f32x4*)tok, out1, out2);
}

// Round 5
// 121.920 us; speedup vs baseline: 2.1426x; 1.0386x over previous
//
#include <hip/hip_runtime.h>

#define ROWS_ 131072      // S*N*B = 16*256*32
#define NNZ_  524288
#define E_    256
#define E4_   64          // E/4 float4s per row
#define LOG2NNZ_ 19       // 2^19 == NNZ_, fixed-iteration binary search

typedef float f32x4 __attribute__((ext_vector_type(4)));

// ---------------------------------------------------------------------------
// Kernel B: dense CSR row_start build. 64 searches per wave (all lanes
// active). ~2-4 us; L2-resident after first sweep.
// ---------------------------------------------------------------------------
__global__ __launch_bounds__(256) void row_ptr_kernel(
    const int* __restrict__ rows, int* __restrict__ row_start) {
    int r = blockIdx.x * blockDim.x + threadIdx.x;
    if (r > ROWS_) return;
    int lo = 0, hi = NNZ_;
    #pragma unroll
    for (int it = 0; it < LOG2NNZ_; ++it) {
        int mid = (lo + hi) >> 1;
        if (rows[mid] < r) lo = mid + 1; else hi = mid;
    }
    row_start[r] = lo;
}

// ---------------------------------------------------------------------------
// Kernel F: one wave per output row, both outputs for that row.
// SINGLE CHANGE vs round 4: output stores are NONTEMPORAL so the 268 MB
// write stream does not allocate in the 256 MiB Infinity Cache — keeps the
// 51 MB tok table L3-resident (round-3 counters: FETCH 254 MB = tok
// re-fetched ~4-5x from HBM due to write-stream eviction).
// ---------------------------------------------------------------------------
__global__ __launch_bounds__(256) void fused_row_kernel(
    const int*   __restrict__ node_idx,
    const int*   __restrict__ row_start,
    const int*   __restrict__ cols,
    const float* __restrict__ vals,
    const f32x4* __restrict__ w,
    const f32x4* __restrict__ tok,
    f32x4*       __restrict__ out1,
    f32x4*       __restrict__ out2) {

    int gtid = blockIdx.x * blockDim.x + threadIdx.x;
    int row  = gtid >> 6;
    int lane = threadIdx.x & 63;

    // ---- dense node-embed half ----
    int node = node_idx[row];                 // wave-uniform
    f32x4 t0 = w[node * E4_ + lane];          // 128 KiB table, L2-hit
    __builtin_nontemporal_store(t0, &out1[(size_t)row * E4_ + lane]);

    // ---- SpMM half ----
    int start = row_start[row];
    int end   = row_start[row + 1];
    int cnt   = end - start;

    f32x4 acc = (f32x4)(0.f);
    for (int base = 0; base < cnt; base += 64) {
        int n = cnt - base; if (n > 64) n = 64;
        int   idx = start + base + lane;
        int   c_l = (lane < n) ? cols[idx] : 0;
        float v_l = (lane < n) ? vals[idx] : 0.f;
        for (int j = 0; j < n; ++j) {
            int   c = __builtin_amdgcn_readlane(c_l, j);   // SGPR col -> saddr gather
            int   vbits = __builtin_amdgcn_readlane(__float_as_int(v_l), j);
            float v = __int_as_float(vbits);
            f32x4 t = tok[c * E4_ + lane];                 // coalesced 1 KiB gather
            acc += v * t;
        }
    }
    __builtin_nontemporal_store(acc, &out2[(size_t)row * E4_ + lane]);
}

extern "C" void kernel_launch(void* const* d_in, const int* in_sizes, int n_in,
                              void* d_out, int out_size, void* d_ws, size_t ws_size,
                              hipStream_t stream) {
    const int*   node_idx  = (const int*)d_in[0];
    const int*   spmm_rows = (const int*)d_in[1];
    const int*   spmm_cols = (const int*)d_in[2];
    const float* spmm_vals = (const float*)d_in[3];
    const float* node_w    = (const float*)d_in[4];
    const float* tok       = (const float*)d_in[5];

    f32x4* out1 = (f32x4*)d_out;                     // node_embed
    f32x4* out2 = out1 + (size_t)ROWS_ * E4_;        // node_val_embed
    int*   row_start = (int*)d_ws;                   // (ROWS_+1) ints

    row_ptr_kernel<<<(ROWS_ + 1 + 255) / 256, 256, 0, stream>>>(
        spmm_rows, row_start);

    // one wave per row, 4 waves per block -> 32768 blocks
    fused_row_kernel<<<ROWS_ / 4, 256, 0, stream>>>(
        node_idx, row_start, spmm_cols, spmm_vals,
        (const f32x4*)node_w, (const f32x4*)tok, out1, out2);
}

// Round 6
// 121.761 us; speedup vs baseline: 2.1454x; 1.0013x over previous
//
#include <hip/hip_runtime.h>

#define ROWS_ 131072      // S*N*B = 16*256*32
#define NNZ_  524288
#define E4_   64          // E/4 float4s per row
#define LOG2NNZ_ 19       // 2^19 == NNZ_

typedef float f32x4 __attribute__((ext_vector_type(4)));

// ---------------------------------------------------------------------------
// Kernel B: dense CSR row_start build (64 active searches per wave).
// ---------------------------------------------------------------------------
__global__ __launch_bounds__(256) void row_ptr_kernel(
    const int* __restrict__ rows, int* __restrict__ row_start) {
    int r = blockIdx.x * blockDim.x + threadIdx.x;
    if (r > ROWS_) return;
    int lo = 0, hi = NNZ_;
    #pragma unroll
    for (int it = 0; it < LOG2NNZ_; ++it) {
        int mid = (lo + hi) >> 1;
        if (rows[mid] < r) lo = mid + 1; else hi = mid;
    }
    row_start[r] = lo;
}

// ---------------------------------------------------------------------------
// Kernel F: one wave per TWO adjacent output rows.
// Changes vs round 5 (targeting exposed gather latency / MLP):
//  - inner gather loop unrolled x4 with predication -> 4 independent 1 KiB
//    gathers in flight per iteration instead of load->waitcnt->fma serial.
//  - adjacent row pair shares one contiguous (col,val) preload (sorted COO:
//    end(r0) == start(r1)); accumulator chosen branch-free by zeroing the
//    inactive row's scalar v (VALU is ~15% busy, FMA duplication is free).
// ---------------------------------------------------------------------------
__global__ __launch_bounds__(256) void fused_row2_kernel(
    const int*   __restrict__ node_idx,
    const int*   __restrict__ row_start,
    const int*   __restrict__ cols,
    const float* __restrict__ vals,
    const f32x4* __restrict__ w,
    const f32x4* __restrict__ tok,
    f32x4*       __restrict__ out1,
    f32x4*       __restrict__ out2) {

    int gtid = blockIdx.x * blockDim.x + threadIdx.x;
    int wid  = gtid >> 6;            // 0..65535, one wave -> rows 2w, 2w+1
    int lane = threadIdx.x & 63;
    int r0   = wid * 2;
    int r1   = r0 + 1;

    // wave-uniform row bounds
    int s0 = row_start[r0];
    int e0 = row_start[r1];
    int e1 = row_start[r0 + 2];

    // ---- dense node-embed half (both rows) ----
    int n0 = node_idx[r0];
    int n1 = node_idx[r1];
    f32x4 w0 = w[n0 * E4_ + lane];   // 128 KiB table, L2-hit
    f32x4 w1 = w[n1 * E4_ + lane];
    __builtin_nontemporal_store(w0, &out1[(size_t)r0 * E4_ + lane]);
    __builtin_nontemporal_store(w1, &out1[(size_t)r1 * E4_ + lane]);

    // ---- SpMM half: combined range [s0, e1) ----
    int cnt0 = e0 - s0;              // nnz belonging to r0
    int cntT = e1 - s0;              // total for the pair

    f32x4 acc0 = (f32x4)(0.f);
    f32x4 acc1 = (f32x4)(0.f);

    for (int base = 0; base < cntT; base += 64) {
        int rem = cntT - base;
        int nn  = rem > 64 ? 64 : rem;
        int idx = s0 + base + lane;
        bool valid = lane < nn;
        int   c_l = valid ? cols[idx] : 0;     // one coalesced preload
        float v_l = valid ? vals[idx] : 0.f;   // invalid lanes: c=0, v=0

        for (int j = 0; j < nn; j += 4) {
            // broadcast 4 (col,val) pairs; lanes >= nn hold (0, 0.0f)
            int   ca = __builtin_amdgcn_readlane(c_l, j);
            int   cb = __builtin_amdgcn_readlane(c_l, j + 1);
            int   cc = __builtin_amdgcn_readlane(c_l, j + 2);
            int   cd = __builtin_amdgcn_readlane(c_l, j + 3);
            float va = __int_as_float(__builtin_amdgcn_readlane(__float_as_int(v_l), j));
            float vb = __int_as_float(__builtin_amdgcn_readlane(__float_as_int(v_l), j + 1));
            float vc = __int_as_float(__builtin_amdgcn_readlane(__float_as_int(v_l), j + 2));
            float vd = __int_as_float(__builtin_amdgcn_readlane(__float_as_int(v_l), j + 3));

            // 4 independent gathers in flight
            f32x4 ta = tok[ca * E4_ + lane];
            f32x4 tb = tok[cb * E4_ + lane];
            f32x4 tc = tok[cc * E4_ + lane];
            f32x4 td = tok[cd * E4_ + lane];

            int p = base + j;
            // branch-free accumulator select: zero the inactive row's scalar
            float a0 = (p     < cnt0) ? va : 0.f, a1 = va - a0;
            float b0 = (p + 1 < cnt0) ? vb : 0.f, b1 = vb - b0;
            float c0 = (p + 2 < cnt0) ? vc : 0.f, c1 = vc - c0;
            float d0 = (p + 3 < cnt0) ? vd : 0.f, d1 = vd - d0;

            acc0 += a0 * ta;  acc1 += a1 * ta;
            acc0 += b0 * tb;  acc1 += b1 * tb;
            acc0 += c0 * tc;  acc1 += c1 * tc;
            acc0 += d0 * td;  acc1 += d1 * td;
        }
    }
    __builtin_nontemporal_store(acc0, &out2[(size_t)r0 * E4_ + lane]);
    __builtin_nontemporal_store(acc1, &out2[(size_t)r1 * E4_ + lane]);
}

extern "C" void kernel_launch(void* const* d_in, const int* in_sizes, int n_in,
                              void* d_out, int out_size, void* d_ws, size_t ws_size,
                              hipStream_t stream) {
    const int*   node_idx  = (const int*)d_in[0];
    const int*   spmm_rows = (const int*)d_in[1];
    const int*   spmm_cols = (const int*)d_in[2];
    const float* spmm_vals = (const float*)d_in[3];
    const float* node_w    = (const float*)d_in[4];
    const float* tok       = (const float*)d_in[5];

    f32x4* out1 = (f32x4*)d_out;                     // node_embed
    f32x4* out2 = out1 + (size_t)ROWS_ * E4_;        // node_val_embed
    int*   row_start = (int*)d_ws;                   // (ROWS_+1) ints

    row_ptr_kernel<<<(ROWS_ + 1 + 255) / 256, 256, 0, stream>>>(
        spmm_rows, row_start);

    // 65536 waves (one per row-pair), 4 waves per block -> 16384 blocks
    fused_row2_kernel<<<16384, 256, 0, stream>>>(
        node_idx, row_start, spmm_cols, spmm_vals,
        (const f32x4*)node_w, (const f32x4*)tok, out1, out2);
}

// Round 7
// 95.900 us; speedup vs baseline: 2.7239x; 1.2697x over previous
//
#include <hip/hip_runtime.h>

#define ROWS_ 131072      // S*N*B = 16*256*32
#define NNZ_  524288
#define E4_   64          // f32x4 per output row (E=256)
#define LOG2NNZ_ 19       // 2^19 == NNZ_
#define RP_BLOCKS_ 513    // ceil((ROWS_+1)/256) binary-search blocks
#define CONV_BLOCKS_ 6250 // 50000*256 f32 / (8 per thread * 256 thr)
#define TOKB_OFF_ (1u << 20)   // bf16 tok copy at d_ws + 1 MiB

typedef float f32x4 __attribute__((ext_vector_type(4)));
typedef unsigned int u32x2 __attribute__((ext_vector_type(2)));
typedef unsigned int u32x4 __attribute__((ext_vector_type(4)));

// ---------------------------------------------------------------------------
// Prologue: two independent jobs in one launch (block-range split):
//  blocks [0, RP_BLOCKS_):   dense CSR row_start build (binary search)
//  blocks [RP_BLOCKS_, ...): convert val_tok_embed f32 -> bf16 (RTNE) into
//                            workspace. NT loads (don't cache the f32 table);
//                            normal stores (DO want the 25.6 MB bf16 copy
//                            L3-resident for the gather phase).
// ---------------------------------------------------------------------------
__global__ __launch_bounds__(256) void prologue_kernel(
    const int*  __restrict__ rows,
    int*        __restrict__ row_start,
    const u32x4* __restrict__ tok_f32,     // 8 floats per 2 entries
    u32x4*      __restrict__ tok_bf16) {   // 8 bf16 per entry

    if (blockIdx.x < RP_BLOCKS_) {
        int r = blockIdx.x * 256 + threadIdx.x;
        if (r > ROWS_) return;
        int lo = 0, hi = NNZ_;
        #pragma unroll
        for (int it = 0; it < LOG2NNZ_; ++it) {
            int mid = (lo + hi) >> 1;
            if (rows[mid] < r) lo = mid + 1; else hi = mid;
        }
        row_start[r] = lo;
    } else {
        int t = (blockIdx.x - RP_BLOCKS_) * 256 + threadIdx.x;  // 8 floats each
        u32x4 a = __builtin_nontemporal_load(&tok_f32[2 * t]);
        u32x4 b = __builtin_nontemporal_load(&tok_f32[2 * t + 1]);
        u32x4 o;
        #pragma unroll
        for (int k = 0; k < 2; ++k) {
            u32x4 s = k ? b : a;
            unsigned r0 = (s[0] + 0x7FFFu + ((s[0] >> 16) & 1u)) >> 16;  // RTNE
            unsigned r1 = (s[1] + 0x7FFFu + ((s[1] >> 16) & 1u)) >> 16;
            unsigned r2 = (s[2] + 0x7FFFu + ((s[2] >> 16) & 1u)) >> 16;
            unsigned r3 = (s[3] + 0x7FFFu + ((s[3] >> 16) & 1u)) >> 16;
            o[2 * k]     = r0 | (r1 << 16);
            o[2 * k + 1] = r2 | (r3 << 16);
        }
        tok_bf16[t] = o;
    }
}

// ---------------------------------------------------------------------------
// Fused main kernel: one wave per output row, both outputs.
//  - out1: node-embed gather from the 128 KiB f32 table (L2-hit), NT store.
//  - out2: SpMM over bf16 tok copy — 512 B/row gathers (half the traffic,
//    half the line count, half the L3 working set vs f32), x4-unrolled
//    independent gathers via readlane-broadcast (col,val), NT store.
// ---------------------------------------------------------------------------
__global__ __launch_bounds__(256) void fused_row_kernel(
    const int*   __restrict__ node_idx,
    const int*   __restrict__ row_start,
    const int*   __restrict__ cols,
    const float* __restrict__ vals,
    const f32x4* __restrict__ w,
    const u32x2* __restrict__ tokb,        // 4 bf16 per entry, 64/row
    f32x4*       __restrict__ out1,
    f32x4*       __restrict__ out2) {

    int gtid = blockIdx.x * blockDim.x + threadIdx.x;
    int row  = gtid >> 6;
    int lane = threadIdx.x & 63;

    // ---- dense node-embed half ----
    int node = node_idx[row];                 // wave-uniform
    f32x4 t0 = w[node * E4_ + lane];
    __builtin_nontemporal_store(t0, &out1[(size_t)row * E4_ + lane]);

    // ---- SpMM half ----
    int start = row_start[row];
    int end   = row_start[row + 1];
    int cnt   = end - start;

    f32x4 acc = (f32x4)(0.f);
    for (int base = 0; base < cnt; base += 64) {
        int rem = cnt - base;
        int nn  = rem > 64 ? 64 : rem;
        int idx = start + base + lane;
        bool valid = lane < nn;
        int   c_l = valid ? cols[idx] : 0;     // pad: col 0, val 0
        float v_l = valid ? vals[idx] : 0.f;

        for (int j = 0; j < nn; j += 4) {
            int   ca = __builtin_amdgcn_readlane(c_l, j);
            int   cb = __builtin_amdgcn_readlane(c_l, j + 1);
            int   cc = __builtin_amdgcn_readlane(c_l, j + 2);
            int   cd = __builtin_amdgcn_readlane(c_l, j + 3);
            float va = __int_as_float(__builtin_amdgcn_readlane(__float_as_int(v_l), j));
            float vb = __int_as_float(__builtin_amdgcn_readlane(__float_as_int(v_l), j + 1));
            float vc = __int_as_float(__builtin_amdgcn_readlane(__float_as_int(v_l), j + 2));
            float vd = __int_as_float(__builtin_amdgcn_readlane(__float_as_int(v_l), j + 3));

            // 4 independent 512 B gathers in flight
            u32x2 ga = tokb[(size_t)ca * E4_ + lane];
            u32x2 gb = tokb[(size_t)cb * E4_ + lane];
            u32x2 gc = tokb[(size_t)cc * E4_ + lane];
            u32x2 gd = tokb[(size_t)cd * E4_ + lane];

            f32x4 ta, tb, tc, td;
            ta[0] = __int_as_float(ga[0] << 16); ta[1] = __int_as_float(ga[0] & 0xFFFF0000u);
            ta[2] = __int_as_float(ga[1] << 16); ta[3] = __int_as_float(ga[1] & 0xFFFF0000u);
            tb[0] = __int_as_float(gb[0] << 16); tb[1] = __int_as_float(gb[0] & 0xFFFF0000u);
            tb[2] = __int_as_float(gb[1] << 16); tb[3] = __int_as_float(gb[1] & 0xFFFF0000u);
            tc[0] = __int_as_float(gc[0] << 16); tc[1] = __int_as_float(gc[0] & 0xFFFF0000u);
            tc[2] = __int_as_float(gc[1] << 16); tc[3] = __int_as_float(gc[1] & 0xFFFF0000u);
            td[0] = __int_as_float(gd[0] << 16); td[1] = __int_as_float(gd[0] & 0xFFFF0000u);
            td[2] = __int_as_float(gd[1] << 16); td[3] = __int_as_float(gd[1] & 0xFFFF0000u);

            acc += va * ta;
            acc += vb * tb;
            acc += vc * tc;
            acc += vd * td;
        }
    }
    __builtin_nontemporal_store(acc, &out2[(size_t)row * E4_ + lane]);
}

extern "C" void kernel_launch(void* const* d_in, const int* in_sizes, int n_in,
                              void* d_out, int out_size, void* d_ws, size_t ws_size,
                              hipStream_t stream) {
    const int*   node_idx  = (const int*)d_in[0];
    const int*   spmm_rows = (const int*)d_in[1];
    const int*   spmm_cols = (const int*)d_in[2];
    const float* spmm_vals = (const float*)d_in[3];
    const float* node_w    = (const float*)d_in[4];
    const float* tok       = (const float*)d_in[5];

    f32x4* out1 = (f32x4*)d_out;                     // node_embed
    f32x4* out2 = out1 + (size_t)ROWS_ * E4_;        // node_val_embed
    int*   row_start = (int*)d_ws;                   // (ROWS_+1) ints
    u32x4* tok_bf16  = (u32x4*)((char*)d_ws + TOKB_OFF_);  // 25.6 MB

    prologue_kernel<<<RP_BLOCKS_ + CONV_BLOCKS_, 256, 0, stream>>>(
        spmm_rows, row_start, (const u32x4*)tok, tok_bf16);

    // one wave per row, 4 waves per block -> 32768 blocks
    fused_row_kernel<<<ROWS_ / 4, 256, 0, stream>>>(
        node_idx, row_start, spmm_cols, spmm_vals,
        (const f32x4*)node_w, (const u32x2*)tok_bf16, out1, out2);
}

// Round 8
// 93.458 us; speedup vs baseline: 2.7951x; 1.0261x over previous
//
#include <hip/hip_runtime.h>

#define ROWS_ 131072      // S*N*B = 16*256*32
#define NNZ_  524288
#define E4_   64          // f32x4 per output row (E=256)
#define LOG2NNZ_ 19       // 2^19 == NNZ_
#define CONV_BLOCKS_ 6250 // 50000*256 f32 / (8 per thread * 256 thr)
#define RP_BLOCKS_   513  // ceil((ROWS_+1)/256)
#define OUT1_BLOCKS_ 32768 // ROWS_*64 f32x4 / 256 thr
#define TOKB_OFF_ (1u << 20)   // bf16 tok copy at d_ws + 1 MiB

typedef float f32x4 __attribute__((ext_vector_type(4)));
typedef unsigned int u32x2 __attribute__((ext_vector_type(2)));
typedef unsigned int u32x4 __attribute__((ext_vector_type(4)));

// ---------------------------------------------------------------------------
// K1 — three independent jobs, block-range split, so the tok f32->bf16
// conversion (51 MB read + 26 MB write) hides under the 134 MB out1 write
// stream instead of running serially before it:
//   [0, CONV)            : val_tok_embed f32 -> bf16 (RTNE) into workspace
//   [CONV, CONV+RP)      : dense CSR row_start build (binary search)
//   [CONV+RP, +OUT1)     : out1 dense node-embed gather + NT store
// ---------------------------------------------------------------------------
__global__ __launch_bounds__(256) void k1_kernel(
    const int*   __restrict__ rows,
    int*         __restrict__ row_start,
    const u32x4* __restrict__ tok_f32,
    u32x4*       __restrict__ tok_bf16,
    const int*   __restrict__ node_idx,
    const f32x4* __restrict__ w,
    f32x4*       __restrict__ out1) {

    int bid = blockIdx.x;
    if (bid < CONV_BLOCKS_) {
        int t = bid * 256 + threadIdx.x;               // 8 floats each
        u32x4 a = __builtin_nontemporal_load(&tok_f32[2 * t]);
        u32x4 b = __builtin_nontemporal_load(&tok_f32[2 * t + 1]);
        u32x4 o;
        #pragma unroll
        for (int k = 0; k < 2; ++k) {
            u32x4 s = k ? b : a;
            unsigned r0 = (s[0] + 0x7FFFu + ((s[0] >> 16) & 1u)) >> 16;  // RTNE
            unsigned r1 = (s[1] + 0x7FFFu + ((s[1] >> 16) & 1u)) >> 16;
            unsigned r2 = (s[2] + 0x7FFFu + ((s[2] >> 16) & 1u)) >> 16;
            unsigned r3 = (s[3] + 0x7FFFu + ((s[3] >> 16) & 1u)) >> 16;
            o[2 * k]     = r0 | (r1 << 16);
            o[2 * k + 1] = r2 | (r3 << 16);
        }
        tok_bf16[t] = o;                               // keep L3-resident
    } else if (bid < CONV_BLOCKS_ + RP_BLOCKS_) {
        int r = (bid - CONV_BLOCKS_) * 256 + threadIdx.x;
        if (r > ROWS_) return;
        int lo = 0, hi = NNZ_;
        #pragma unroll
        for (int it = 0; it < LOG2NNZ_; ++it) {
            int mid = (lo + hi) >> 1;
            if (rows[mid] < r) lo = mid + 1; else hi = mid;
        }
        row_start[r] = lo;
    } else {
        int tid  = (bid - CONV_BLOCKS_ - RP_BLOCKS_) * 256 + threadIdx.x;
        int row  = tid >> 6;
        int l    = tid & 63;
        int node = node_idx[row];                      // wave-uniform
        f32x4 t0 = w[node * E4_ + l];                  // 128 KiB table, L2-hit
        __builtin_nontemporal_store(t0, &out1[tid]);
    }
}

// ---------------------------------------------------------------------------
// K2 — SpMM only: one wave per output row. (col,val) preloaded 64-wide and
// broadcast via readlane; x4-unrolled independent 512 B bf16 gathers from
// the L3-resident workspace copy; NT store of the f32 row.
// ---------------------------------------------------------------------------
__global__ __launch_bounds__(256) void spmm_kernel(
    const int*   __restrict__ row_start,
    const int*   __restrict__ cols,
    const float* __restrict__ vals,
    const u32x2* __restrict__ tokb,        // 4 bf16 per entry, 64/row
    f32x4*       __restrict__ out2) {

    int gtid = blockIdx.x * blockDim.x + threadIdx.x;
    int row  = gtid >> 6;
    int lane = threadIdx.x & 63;

    int start = row_start[row];
    int end   = row_start[row + 1];
    int cnt   = end - start;

    f32x4 acc = (f32x4)(0.f);
    for (int base = 0; base < cnt; base += 64) {
        int rem = cnt - base;
        int nn  = rem > 64 ? 64 : rem;
        int idx = start + base + lane;
        bool valid = lane < nn;
        int   c_l = valid ? cols[idx] : 0;     // pad: col 0, val 0
        float v_l = valid ? vals[idx] : 0.f;

        for (int j = 0; j < nn; j += 4) {
            int   ca = __builtin_amdgcn_readlane(c_l, j);
            int   cb = __builtin_amdgcn_readlane(c_l, j + 1);
            int   cc = __builtin_amdgcn_readlane(c_l, j + 2);
            int   cd = __builtin_amdgcn_readlane(c_l, j + 3);
            float va = __int_as_float(__builtin_amdgcn_readlane(__float_as_int(v_l), j));
            float vb = __int_as_float(__builtin_amdgcn_readlane(__float_as_int(v_l), j + 1));
            float vc = __int_as_float(__builtin_amdgcn_readlane(__float_as_int(v_l), j + 2));
            float vd = __int_as_float(__builtin_amdgcn_readlane(__float_as_int(v_l), j + 3));

            u32x2 ga = tokb[(size_t)ca * E4_ + lane];  // 4 independent gathers
            u32x2 gb = tokb[(size_t)cb * E4_ + lane];
            u32x2 gc = tokb[(size_t)cc * E4_ + lane];
            u32x2 gd = tokb[(size_t)cd * E4_ + lane];

            f32x4 ta, tb, tc, td;
            ta[0] = __int_as_float(ga[0] << 16); ta[1] = __int_as_float(ga[0] & 0xFFFF0000u);
            ta[2] = __int_as_float(ga[1] << 16); ta[3] = __int_as_float(ga[1] & 0xFFFF0000u);
            tb[0] = __int_as_float(gb[0] << 16); tb[1] = __int_as_float(gb[0] & 0xFFFF0000u);
            tb[2] = __int_as_float(gb[1] << 16); tb[3] = __int_as_float(gb[1] & 0xFFFF0000u);
            tc[0] = __int_as_float(gc[0] << 16); tc[1] = __int_as_float(gc[0] & 0xFFFF0000u);
            tc[2] = __int_as_float(gc[1] << 16); tc[3] = __int_as_float(gc[1] & 0xFFFF0000u);
            td[0] = __int_as_float(gd[0] << 16); td[1] = __int_as_float(gd[0] & 0xFFFF0000u);
            td[2] = __int_as_float(gd[1] << 16); td[3] = __int_as_float(gd[1] & 0xFFFF0000u);

            acc += va * ta;
            acc += vb * tb;
            acc += vc * tc;
            acc += vd * td;
        }
    }
    __builtin_nontemporal_store(acc, &out2[(size_t)row * E4_ + lane]);
}

extern "C" void kernel_launch(void* const* d_in, const int* in_sizes, int n_in,
                              void* d_out, int out_size, void* d_ws, size_t ws_size,
                              hipStream_t stream) {
    const int*   node_idx  = (const int*)d_in[0];
    const int*   spmm_rows = (const int*)d_in[1];
    const int*   spmm_cols = (const int*)d_in[2];
    const float* spmm_vals = (const float*)d_in[3];
    const float* node_w    = (const float*)d_in[4];
    const float* tok       = (const float*)d_in[5];

    f32x4* out1 = (f32x4*)d_out;                     // node_embed
    f32x4* out2 = out1 + (size_t)ROWS_ * E4_;        // node_val_embed
    int*   row_start = (int*)d_ws;                   // (ROWS_+1) ints
    u32x4* tok_bf16  = (u32x4*)((char*)d_ws + TOKB_OFF_);  // 25.6 MB

    k1_kernel<<<CONV_BLOCKS_ + RP_BLOCKS_ + OUT1_BLOCKS_, 256, 0, stream>>>(
        spmm_rows, row_start, (const u32x4*)tok, tok_bf16,
        node_idx, (const f32x4*)node_w, out1);

    // one wave per row, 4 waves per block -> 32768 blocks
    spmm_kernel<<<ROWS_ / 4, 256, 0, stream>>>(
        row_start, spmm_cols, spmm_vals, (const u32x2*)tok_bf16, out2);
}